// Round 6
// baseline (1921.677 us; speedup 1.0000x reference)
//
#include <hip/hip_runtime.h>

// Problem constants (from reference setup_inputs)
#define NVOX   4096   // B voxels
#define NMEAS  256    // M measurements
#define NATOMS 512    // K atoms
#define NITER  30

typedef __attribute__((ext_vector_type(8))) short s8v;   // 8 bf16 (4 VGPR) MFMA frag
typedef __attribute__((ext_vector_type(4))) short s4v;
typedef __attribute__((ext_vector_type(4))) float f32x4;

// bf16 round-to-nearest-even split helpers (no NaN/Inf in this problem)
__device__ __forceinline__ unsigned short f2bf(float x) {
    unsigned u = __builtin_bit_cast(unsigned, x);
    u += 0x7fff + ((u >> 16) & 1);
    return (unsigned short)(u >> 16);
}
__device__ __forceinline__ float bf2f(unsigned short b) {
    unsigned u = ((unsigned)b) << 16;
    return __builtin_bit_cast(float, u);
}
// g(v) = (z - u) collapsed through v = x + u :  relu(v-0.1) - min(v,0.1)
__device__ __forceinline__ float g_of(float v) {
    return fmaxf(v - 0.1f, 0.0f) - fminf(v, 0.1f);
}

// ---------------------------------------------------------------------------
// K0: G = I + A*A^T in fp64 (Gd) + fp32 copy (Gf) for the sweep
// ---------------------------------------------------------------------------
__global__ __launch_bounds__(256) void g_kernel_d(const float* __restrict__ A,
                                                  double* __restrict__ Gd,
                                                  float* __restrict__ Gf) {
    __shared__ float arow[NATOMS];
    int i = blockIdx.x;
    for (int k = threadIdx.x; k < NATOMS; k += 256) arow[k] = A[i * NATOMS + k];
    __syncthreads();
    int j = threadIdx.x;
    const float* aj = A + j * NATOMS;
    double s = (i == j) ? 1.0 : 0.0;
#pragma unroll 4
    for (int k = 0; k < NATOMS; ++k) s += (double)arow[k] * (double)aj[k];
    Gd[i * NMEAS + j] = s;
    Gf[i * NMEAS + j] = (float)s;
}

// ---------------------------------------------------------------------------
// K1: SPD inverse of Gf (256x256) via BLOCKED symmetric SWEEP, panel NB=4.
// r5's scalar sweep was barrier-bound: 2650 cyc/pivot vs ~130 compute
// (2 barriers x 16 waves x 256 pivots). Blocked: 64 steps x 2 barriers,
// rank-4 Schur update amortizes the drain. All register indexing is
// compile-time (rule #20); panel staged in LDS with lane-consecutive
// scalar layout U[a][i][rb] -> zero bank conflicts.
// Thread t: rb=t&31 (rows 8rb+i), cb=t>>5 (cols 8cb+j), vals[8][8].
// Panel s: pivots 4s..4s+3; publisher block pcb=s>>1, half ph=(s&1)*4.
//   B = App^{-1} (4x4, redundant per-thread sweep; SPD Schur => pivots>=1)
//   E[j] = B*N_j ; generic: vals[i][j] -= M_i . E[j]
//   row-fix (rb==pcb): vals[ph+ii][j] = E[j][ii]
//   col-fix (cb==pcb): vals[i][ph+a'] = M_i . B[:,a']
//   diag: vals[ph+ii][ph+a'] = -B[ii][a']
// sweep(all pivots) = -G^{-1}; negate on store.
// ---------------------------------------------------------------------------
__global__ __launch_bounds__(1024) void sweep_inverse_blk(const float* __restrict__ src,
                                                          float* __restrict__ dst) {
    __shared__ float U[4][8][32];   // [col-slot a][row-in-block i][rb] : 4 KB
    int t = threadIdx.x;
    int rb = t & 31;
    int cb = t >> 5;
    float vals[8][8];
#pragma unroll
    for (int i = 0; i < 8; ++i) {
        const float* row = &src[(8 * rb + i) * NMEAS + 8 * cb];
        float4 a = *(const float4*)row;
        float4 b = *(const float4*)(row + 4);
        vals[i][0] = a.x; vals[i][1] = a.y; vals[i][2] = a.z; vals[i][3] = a.w;
        vals[i][4] = b.x; vals[i][5] = b.y; vals[i][6] = b.z; vals[i][7] = b.w;
    }

#pragma unroll 1
    for (int s = 0; s < 64; ++s) {
        int pcb = s >> 1;
        int ph  = (s & 1) * 4;
        __syncthreads();              // protect U from previous step's readers
        if (cb == pcb) {              // publish panel: U[a][i][rb] = A[8rb+i][4s+a]
#pragma unroll
            for (int a = 0; a < 4; ++a)
#pragma unroll
                for (int i = 0; i < 8; ++i)
                    U[a][i][rb] = vals[i][ph + a];
        }
        __syncthreads();

        // ---- B = App^{-1} via in-register 4x4 sweep (redundant per thread)
        float P[4][4];
#pragma unroll
        for (int a = 0; a < 4; ++a)
#pragma unroll
            for (int b = 0; b < 4; ++b)
                P[a][b] = U[b][ph + a][pcb];     // App[a][b], uniform reads
#pragma unroll
        for (int p = 0; p < 4; ++p) {
            float inv = 1.0f / P[p][p];
            float rv[4], cv[4];
#pragma unroll
            for (int a = 0; a < 4; ++a) rv[a] = P[a][p];
#pragma unroll
            for (int b = 0; b < 4; ++b) cv[b] = P[p][b] * inv;
#pragma unroll
            for (int a = 0; a < 4; ++a)
#pragma unroll
                for (int b = 0; b < 4; ++b) P[a][b] -= rv[a] * cv[b];
#pragma unroll
            for (int b = 0; b < 4; ++b) P[p][b] = cv[b];
#pragma unroll
            for (int a = 0; a < 4; ++a) P[a][p] = rv[a] * inv;
            P[p][p] = -inv;
        }
        float B[4][4];                 // P now holds -App^{-1}
#pragma unroll
        for (int a = 0; a < 4; ++a)
#pragma unroll
            for (int b = 0; b < 4; ++b) B[a][b] = -P[a][b];

        // ---- E[j][a] = sum_b B[a][b] * N_j[b],  N_j[b] = A[8cb+j][4s+b]
        float E[8][4];
#pragma unroll
        for (int j = 0; j < 8; ++j) {
            float n0 = U[0][j][cb], n1 = U[1][j][cb], n2 = U[2][j][cb], n3 = U[3][j][cb];
#pragma unroll
            for (int a = 0; a < 4; ++a)
                E[j][a] = B[a][0] * n0 + B[a][1] * n1 + B[a][2] * n2 + B[a][3] * n3;
        }

        // ---- generic rank-4 update: vals[i][j] -= M_i . E[j]
#pragma unroll
        for (int i = 0; i < 8; ++i) {
            float m0 = U[0][i][rb], m1 = U[1][i][rb], m2 = U[2][i][rb], m3 = U[3][i][rb];
#pragma unroll
            for (int j = 0; j < 8; ++j)
                vals[i][j] -= m0 * E[j][0] + m1 * E[j][1] + m2 * E[j][2] + m3 * E[j][3];
        }

        // ---- pivot-row fixup: rows 4s..4s+3 -> B * Apq  (= E^T slice)
        if (rb == pcb) {
#pragma unroll
            for (int ii = 0; ii < 4; ++ii)
#pragma unroll
                for (int j = 0; j < 8; ++j)
                    vals[ph + ii][j] = E[j][ii];
        }
        // ---- pivot-col fixup: cols 4s..4s+3 -> Aqp * B
        if (cb == pcb) {
#pragma unroll
            for (int i = 0; i < 8; ++i) {
                float m0 = U[0][i][rb], m1 = U[1][i][rb], m2 = U[2][i][rb], m3 = U[3][i][rb];
#pragma unroll
                for (int a = 0; a < 4; ++a)
                    vals[i][ph + a] = m0 * B[0][a] + m1 * B[1][a] + m2 * B[2][a] + m3 * B[3][a];
            }
        }
        // ---- diagonal block: -App^{-1}
        if (rb == pcb && cb == pcb) {
#pragma unroll
            for (int ii = 0; ii < 4; ++ii)
#pragma unroll
                for (int a = 0; a < 4; ++a)
                    vals[ph + ii][ph + a] = -B[ii][a];
        }
    }
    // sweep(all) == -G^{-1}  ->  negate on store
#pragma unroll
    for (int i = 0; i < 8; ++i)
#pragma unroll
        for (int j = 0; j < 8; ++j)
            dst[(8 * rb + i) * NMEAS + 8 * cb + j] = -vals[i][j];
}

// ---------------------------------------------------------------------------
// fp64 Newton refinement:  P = Gd @ X ;  Xn = 2X - X @ P   (X input fp32/fp64)
// (fp32 Newton was the r3/r4 bug: cancellation noise ~cond(G)*eps32)
// ---------------------------------------------------------------------------
template <typename TB>
__global__ __launch_bounds__(256) void mm_gd(const double* __restrict__ Gd,
                                             const TB* __restrict__ X,
                                             double* __restrict__ P) {
    __shared__ __align__(16) double row[NMEAS];
    int i = blockIdx.x;
    row[threadIdx.x] = Gd[i * NMEAS + threadIdx.x];
    __syncthreads();
    int j = threadIdx.x;
    double s = 0.0;
#pragma unroll 4
    for (int k = 0; k < NMEAS; ++k) s += row[k] * (double)X[k * NMEAS + j];
    P[i * NMEAS + j] = s;
}

template <typename TB>
__global__ __launch_bounds__(256) void upd_newton(const TB* __restrict__ X,
                                                  const double* __restrict__ P,
                                                  double* __restrict__ Xn) {
    __shared__ __align__(16) double row[NMEAS];
    int i = blockIdx.x;
    row[threadIdx.x] = (double)X[i * NMEAS + threadIdx.x];
    __syncthreads();
    int j = threadIdx.x;
    double s = 0.0;
#pragma unroll 4
    for (int k = 0; k < NMEAS; ++k) s += row[k] * P[k * NMEAS + j];
    Xn[i * NMEAS + j] = 2.0 * row[j] - s;
}

// ---------------------------------------------------------------------------
// K2: Hd = X2d @ A   (fp64 [256][256] @ fp32 [256][512] -> fp64 [256][512])
// ---------------------------------------------------------------------------
__global__ __launch_bounds__(256) void h_kernel_d(const double* __restrict__ Gi,
                                                  const float* __restrict__ A,
                                                  double* __restrict__ H) {
    __shared__ __align__(16) double grow[NMEAS];
    int i = blockIdx.x;
    grow[threadIdx.x] = Gi[i * NMEAS + threadIdx.x];
    __syncthreads();
    int k0 = threadIdx.x;
    double s0 = 0.0, s1 = 0.0;
#pragma unroll 4
    for (int j = 0; j < NMEAS; ++j) {
        double g = grow[j];
        s0 += g * (double)A[j * NATOMS + k0];
        s1 += g * (double)A[j * NATOMS + k0 + 256];
    }
    H[i * NATOMS + k0] = s0;
    H[i * NATOMS + k0 + 256] = s1;
}

// ---------------------------------------------------------------------------
// K3: W = I - A^T @ Hd  (fp64 accumulate), stored as bf16 hi/lo split
// ---------------------------------------------------------------------------
__global__ __launch_bounds__(256) void w_kernel_d(const float* __restrict__ A,
                                                  const double* __restrict__ H,
                                                  unsigned short* __restrict__ Whg,
                                                  unsigned short* __restrict__ Wlg) {
    __shared__ __align__(16) double acol[NMEAS];
    int p = blockIdx.x;
    acol[threadIdx.x] = (double)A[threadIdx.x * NATOMS + p];
    __syncthreads();
    int q0 = threadIdx.x;
    double s0 = 0.0, s1 = 0.0;
#pragma unroll 4
    for (int m = 0; m < NMEAS; ++m) {
        double a = acol[m];
        s0 += a * H[m * NATOMS + q0];
        s1 += a * H[m * NATOMS + q0 + 256];
    }
    double w0 = ((p == q0)       ? 1.0 : 0.0) - s0;
    double w1 = ((p == q0 + 256) ? 1.0 : 0.0) - s1;
    unsigned short h0 = f2bf((float)w0), h1 = f2bf((float)w1);
    Whg[p * NATOMS + q0]       = h0;
    Wlg[p * NATOMS + q0]       = f2bf((float)(w0 - (double)bf2f(h0)));
    Whg[p * NATOMS + q0 + 256] = h1;
    Wlg[p * NATOMS + q0 + 256] = f2bf((float)(w1 - (double)bf2f(h1)));
}

// ---------------------------------------------------------------------------
// K4: Delta0 = AtY (= t_1, since t_0 = 0), stored split bf16 hi/lo,
//     TRANSPOSED to [4096 voxels][512 atoms] for k-contiguous staging.
// AtY[k][b] = sum_m A[m][k] * Y[b][m]
// ---------------------------------------------------------------------------
__global__ __launch_bounds__(256) void aty_kernel(const float* __restrict__ A,
                                                  const float* __restrict__ Y,
                                                  unsigned short* __restrict__ Dh0,
                                                  unsigned short* __restrict__ Dl0) {
    __shared__ __align__(16) float At[64][65];
    __shared__ __align__(16) float Yt[64][65];
    int b0 = blockIdx.x * 64, k0 = blockIdx.y * 64;
    int t = threadIdx.x, tx = t & 15, ty = t >> 4;
    float acc[4][4] = {};
    for (int m0 = 0; m0 < NMEAS; m0 += 64) {
        __syncthreads();
        {
            int kk = t & 63, mr = t >> 6;
#pragma unroll
            for (int p = 0; p < 16; ++p)
                At[mr + 4 * p][kk] = A[(m0 + mr + 4 * p) * NATOMS + k0 + kk];
            int mm = t & 63, br = t >> 6;
#pragma unroll
            for (int p = 0; p < 16; ++p)
                Yt[mm][br + 4 * p] = Y[(b0 + br + 4 * p) * NMEAS + m0 + mm];
        }
        __syncthreads();
#pragma unroll 4
        for (int m = 0; m < 64; ++m) {
            float av[4], yv[4];
#pragma unroll
            for (int i = 0; i < 4; ++i) av[i] = At[m][ty * 4 + i];
#pragma unroll
            for (int j = 0; j < 4; ++j) yv[j] = Yt[m][tx * 4 + j];
#pragma unroll
            for (int i = 0; i < 4; ++i)
#pragma unroll
                for (int j = 0; j < 4; ++j) acc[i][j] += av[i] * yv[j];
        }
    }
#pragma unroll
    for (int j = 0; j < 4; ++j) {
        int b = b0 + tx * 4 + j;
        s4v h4, l4;
#pragma unroll
        for (int i = 0; i < 4; ++i) {
            float f = acc[i][j];
            unsigned short h = f2bf(f);
            h4[i] = (short)h;
            l4[i] = (short)f2bf(f - bf2f(h));
        }
        *(s4v*)&Dh0[(long)b * NATOMS + k0 + ty * 4] = h4;
        *(s4v*)&Dl0[(long)b * NATOMS + k0 + ty * 4] = l4;
    }
}

// ---------------------------------------------------------------------------
// K5: one ADMM iteration, DELTA form, bf16-split MFMA, 3 terms
//   (Wh*Dh + Wh*Dl + Wl*Dh; dropped Wl*Dl <= 2^-18 rel):
//   dx = W @ Delta_in            (Delta decays with k -> split error decays)
//   x_k = x_{k-1} + dx ;  v_k = x_k + min(v_{k-1}, 0.1)
//   Delta_out = g(v_k) - g(v_{k-1})    -> split bf16, transposed [n][k]
// LAST: out[b][k] = x_{k-1} + dx  (transposed fp32 write)
// Tile: BM=64 x BN=128, BK=32, 256 thr (4 waves), mfma_f32_16x16x32_bf16.
// ---------------------------------------------------------------------------
template <int FIRST, int LAST>
__global__ __launch_bounds__(256) void admm_delta(
        const unsigned short* __restrict__ Whg,
        const unsigned short* __restrict__ Wlg,
        const unsigned short* __restrict__ Dhg,
        const unsigned short* __restrict__ Dlg,
        float* __restrict__ xbuf,            // fp32 x [512][4096], in-place
        float* __restrict__ vbuf,            // fp32 v [512][4096], in-place (d_out)
        unsigned short* __restrict__ DhOut,
        unsigned short* __restrict__ DlOut,
        float* __restrict__ out) {
    __shared__ __align__(16) char smem[61440];
    unsigned short* Whs = (unsigned short*)smem;      // [2][64*40]
    unsigned short* Wls = Whs + 2 * 64 * 40;          // [2][64*40]
    unsigned short* Dhs = Wls + 2 * 64 * 40;          // [2][128*40]
    unsigned short* Dls = Dhs + 2 * 128 * 40;         // [2][128*40]

    const int t = threadIdx.x;
    const int lane = t & 63, wv = t >> 6;
    const int ln = lane & 15, kg = lane >> 4;
    const int n0 = blockIdx.x * 128, m0 = blockIdx.y * 64;

    const int wm = t >> 2, wslot = t & 3;
    const int tn = t >> 2, tslot = t & 3;

    f32x4 acc[4][2] = {};
    s8v rwh, rwl, rth0, rth1, rtl0, rtl1;

#define GLOAD(kc)                                                                \
    {                                                                            \
        long ko = (long)(kc)*32;                                                 \
        rwh  = *(const s8v*)&Whg[(long)(m0 + wm) * NATOMS + ko + wslot * 8];     \
        rwl  = *(const s8v*)&Wlg[(long)(m0 + wm) * NATOMS + ko + wslot * 8];     \
        rth0 = *(const s8v*)&Dhg[(long)(n0 + tn) * NATOMS + ko + tslot * 8];     \
        rth1 = *(const s8v*)&Dhg[(long)(n0 + 64 + tn) * NATOMS + ko + tslot * 8];\
        rtl0 = *(const s8v*)&Dlg[(long)(n0 + tn) * NATOMS + ko + tslot * 8];     \
        rtl1 = *(const s8v*)&Dlg[(long)(n0 + 64 + tn) * NATOMS + ko + tslot * 8];\
    }
#define DSWRITE(b)                                                  \
    {                                                               \
        *(s8v*)&Whs[(b)*2560 + wm * 40 + wslot * 8] = rwh;          \
        *(s8v*)&Wls[(b)*2560 + wm * 40 + wslot * 8] = rwl;          \
        *(s8v*)&Dhs[(b)*5120 + tn * 40 + tslot * 8] = rth0;         \
        *(s8v*)&Dhs[(b)*5120 + (64 + tn) * 40 + tslot * 8] = rth1;  \
        *(s8v*)&Dls[(b)*5120 + tn * 40 + tslot * 8] = rtl0;         \
        *(s8v*)&Dls[(b)*5120 + (64 + tn) * 40 + tslot * 8] = rtl1;  \
    }

    GLOAD(0);
    DSWRITE(0);
#pragma unroll 1
    for (int c = 0; c < 16; ++c) {
        if (c < 15) GLOAD(c + 1);
        __syncthreads();
        const int b = c & 1;
        const unsigned short* wh = &Whs[b * 2560];
        const unsigned short* wl = &Wls[b * 2560];
        const unsigned short* dh = &Dhs[b * 5120];
        const unsigned short* dl = &Dls[b * 5120];
        s8v ah[4], al[4], bh[2], bl[2];
#pragma unroll
        for (int mi = 0; mi < 4; ++mi) {
            ah[mi] = *(const s8v*)&wh[(mi * 16 + ln) * 40 + kg * 8];
            al[mi] = *(const s8v*)&wl[(mi * 16 + ln) * 40 + kg * 8];
        }
#pragma unroll
        for (int ni = 0; ni < 2; ++ni) {
            int r = wv * 32 + ni * 16 + ln;
            bh[ni] = *(const s8v*)&dh[r * 40 + kg * 8];
            bl[ni] = *(const s8v*)&dl[r * 40 + kg * 8];
        }
#pragma unroll
        for (int mi = 0; mi < 4; ++mi)
#pragma unroll
            for (int ni = 0; ni < 2; ++ni) {
                acc[mi][ni] = __builtin_amdgcn_mfma_f32_16x16x32_bf16(ah[mi], bh[ni], acc[mi][ni], 0, 0, 0);
                acc[mi][ni] = __builtin_amdgcn_mfma_f32_16x16x32_bf16(ah[mi], bl[ni], acc[mi][ni], 0, 0, 0);
                acc[mi][ni] = __builtin_amdgcn_mfma_f32_16x16x32_bf16(al[mi], bh[ni], acc[mi][ni], 0, 0, 0);
            }
        if (c < 15) DSWRITE((c + 1) & 1);
    }
#undef GLOAD
#undef DSWRITE

    __syncthreads();                        // staging LDS dead; reuse as xT [128][68] f32
    float* xT = (float*)smem;

    if (!LAST) {
#pragma unroll
        for (int mi = 0; mi < 4; ++mi)
#pragma unroll
            for (int ni = 0; ni < 2; ++ni) {
                int nn = n0 + wv * 32 + ni * 16 + ln;
                f32x4 dlt;
#pragma unroll
                for (int j = 0; j < 4; ++j) {
                    int m = m0 + mi * 16 + kg * 4 + j;
                    long idx = (long)m * NVOX + nn;
                    float dx = acc[mi][ni][j];
                    float xn, vn, gold;
                    if (FIRST) {
                        xn = dx; vn = xn; gold = 0.0f;   // x0=0, u0=0, v0=0
                    } else {
                        xn = xbuf[idx] + dx;
                        float vp = vbuf[idx];
                        vn = xn + fminf(vp, 0.1f);
                        gold = g_of(vp);
                    }
                    xbuf[idx] = xn;
                    vbuf[idx] = vn;
                    dlt[j] = g_of(vn) - gold;
                }
                int nl = wv * 32 + ni * 16 + ln;
                int ml = mi * 16 + kg * 4;
                *(f32x4*)&xT[nl * 68 + ml] = dlt;
            }
        __syncthreads();
        int nl = t >> 1, seg = t & 1;
#pragma unroll
        for (int q8 = 0; q8 < 4; ++q8) {
            s8v hv, lv;
#pragma unroll
            for (int e = 0; e < 8; ++e) {
                float f = xT[nl * 68 + seg * 32 + q8 * 8 + e];
                unsigned short h = f2bf(f);
                hv[e] = (short)h;
                lv[e] = (short)f2bf(f - bf2f(h));
            }
            *(s8v*)&DhOut[(long)(n0 + nl) * NATOMS + m0 + seg * 32 + q8 * 8] = hv;
            *(s8v*)&DlOut[(long)(n0 + nl) * NATOMS + m0 + seg * 32 + q8 * 8] = lv;
        }
    } else {
        // LAST: out[b][k] = x_{k-1}[k][b] + dx  (transposed fp32 write)
#pragma unroll
        for (int mi = 0; mi < 4; ++mi)
#pragma unroll
            for (int ni = 0; ni < 2; ++ni) {
                int nn = n0 + wv * 32 + ni * 16 + ln;
                f32x4 tv;
#pragma unroll
                for (int j = 0; j < 4; ++j) {
                    int m = m0 + mi * 16 + kg * 4 + j;
                    tv[j] = xbuf[(long)m * NVOX + nn] + acc[mi][ni][j];
                }
                int nl = wv * 32 + ni * 16 + ln;
                int ml = mi * 16 + kg * 4;
                *(f32x4*)&xT[nl * 68 + ml] = tv;
            }
        __syncthreads();
        int nl = t >> 1, seg = t & 1;
#pragma unroll
        for (int q = 0; q < 8; ++q) {
            f32x4 v = *(const f32x4*)&xT[nl * 68 + seg * 32 + q * 4];
            *(f32x4*)&out[(long)(n0 + nl) * NATOMS + m0 + seg * 32 + q * 4] = v;
        }
    }
}

// ---------------------------------------------------------------------------
extern "C" void kernel_launch(void* const* d_in, const int* in_sizes, int n_in,
                              void* d_out, int out_size, void* d_ws, size_t ws_size,
                              hipStream_t stream) {
    const float* Y = (const float*)d_in[0];   // [4096][256]
    const float* A = (const float*)d_in[1];   // [256][512]

    // ws layout (float units), lifetime-checked overlays; total 6946816 floats
    // = 26.5 MiB (r3/r4/r5-proven footprint).
    float* ws = (float*)d_ws;
    double* Gd  = (double*)(ws + 0);        // [0,131072)       dead after step 5
    float*  Gf  = ws + 131072;              // [131072,196608)  dead after sweep
    float*  X0f = ws + 196608;              // [196608,262144)  dead after step 4
    double* X1d = (double*)(ws + 262144);   // [262144,393216)  dead after step 6
    double* Pd  = (double*)(ws + 393216);   // [393216,524288)  dead after step 6
    double* X2d = (double*)(ws + 131072);   // overlays Gf+X0f (both dead)
    double* Hd  = (double*)(ws + 393216);   // [393216,655360) overlays Pd (dead)
    float*  xbuf = ws + 655360;             // [655360,2752512) fp32 x state
    unsigned short* Whg = (unsigned short*)(ws + 0);        // overlays Gd (dead)
    unsigned short* Wlg = (unsigned short*)(ws + 131072);   // overlays X2d (dead after h)
    unsigned short* DAh = (unsigned short*)(ws + 2752512);
    unsigned short* DAl = (unsigned short*)(ws + 3801088);
    unsigned short* DBh = (unsigned short*)(ws + 4849664);
    unsigned short* DBl = (unsigned short*)(ws + 5898240);  // end 6946816
    float* vbuf = (float*)d_out;   // v_k fp32, iters 1..29 (d_out as scratch)
    float* outp = (float*)d_out;   // final output, written by LAST iter only

    g_kernel_d<<<256, 256, 0, stream>>>(A, Gd, Gf);                 // 1
    sweep_inverse_blk<<<1, 1024, 0, stream>>>(Gf, X0f);             // 2
    mm_gd<float><<<256, 256, 0, stream>>>(Gd, X0f, Pd);             // 3
    upd_newton<float><<<256, 256, 0, stream>>>(X0f, Pd, X1d);       // 4
    mm_gd<double><<<256, 256, 0, stream>>>(Gd, X1d, Pd);            // 5
    upd_newton<double><<<256, 256, 0, stream>>>(X1d, Pd, X2d);      // 6
    h_kernel_d<<<256, 256, 0, stream>>>(X2d, A, Hd);                // 7
    w_kernel_d<<<512, 256, 0, stream>>>(A, Hd, Whg, Wlg);           // 8
    aty_kernel<<<dim3(64, 8), 256, 0, stream>>>(A, Y, DAh, DAl);    // 9

    dim3 ig(NVOX / 128, NATOMS / 64);  // (32, 8) = 256 blocks
    unsigned short *ch = DAh, *cl = DAl, *nh = DBh, *nl = DBl;
    // iter 1: Delta_0 = AtY; x1 = W*AtY; v1 = x1; Delta_1 = g(v1)
    admm_delta<1, 0><<<ig, 256, 0, stream>>>(Whg, Wlg, ch, cl, xbuf, vbuf, nh, nl, nullptr);
    { unsigned short* s; s = ch; ch = nh; nh = s; s = cl; cl = nl; nl = s; }
    for (int it = 2; it <= NITER - 1; ++it) {
        admm_delta<0, 0><<<ig, 256, 0, stream>>>(Whg, Wlg, ch, cl, xbuf, vbuf, nh, nl, nullptr);
        unsigned short* s; s = ch; ch = nh; nh = s; s = cl; cl = nl; nl = s;
    }
    // iter 30: x30 = x29 + W*Delta_29, written transposed to d_out
    admm_delta<0, 1><<<ig, 256, 0, stream>>>(Whg, Wlg, ch, cl, xbuf, vbuf, nullptr, nullptr, outp);
}

// Round 7
// 1096.167 us; speedup vs baseline: 1.7531x; 1.7531x over previous
//
#include <hip/hip_runtime.h>

// Problem constants (from reference setup_inputs)
#define NVOX   4096   // B voxels
#define NMEAS  256    // M measurements
#define NATOMS 512    // K atoms
#define NITER  30

typedef __attribute__((ext_vector_type(8))) short s8v;   // 8 bf16 (4 VGPR) MFMA frag
typedef __attribute__((ext_vector_type(4))) short s4v;
typedef __attribute__((ext_vector_type(4))) float f32x4;

// bf16 round-to-nearest-even split helpers (no NaN/Inf in this problem)
__device__ __forceinline__ unsigned short f2bf(float x) {
    unsigned u = __builtin_bit_cast(unsigned, x);
    u += 0x7fff + ((u >> 16) & 1);
    return (unsigned short)(u >> 16);
}
__device__ __forceinline__ float bf2f(unsigned short b) {
    unsigned u = ((unsigned)b) << 16;
    return __builtin_bit_cast(float, u);
}
// g(v) = (z - u) collapsed through v = x + u :  relu(v-0.1) - min(v,0.1)
__device__ __forceinline__ float g_of(float v) {
    return fmaxf(v - 0.1f, 0.0f) - fminf(v, 0.1f);
}

// ---------------------------------------------------------------------------
// K0: G = I + A*A^T in fp64 (Gd) + fp32 copy (Gf) for the sweep
// ---------------------------------------------------------------------------
__global__ __launch_bounds__(256) void g_kernel_d(const float* __restrict__ A,
                                                  double* __restrict__ Gd,
                                                  float* __restrict__ Gf) {
    __shared__ float arow[NATOMS];
    int i = blockIdx.x;
    for (int k = threadIdx.x; k < NATOMS; k += 256) arow[k] = A[i * NATOMS + k];
    __syncthreads();
    int j = threadIdx.x;
    const float* aj = A + j * NATOMS;
    double s = (i == j) ? 1.0 : 0.0;
#pragma unroll 4
    for (int k = 0; k < NATOMS; ++k) s += (double)arow[k] * (double)aj[k];
    Gd[i * NMEAS + j] = s;
    Gf[i * NMEAS + j] = (float)s;
}

// ---------------------------------------------------------------------------
// K1: SPD inverse of Gf (256x256), BLOCKED symmetric SWEEP, panel NB=4.
// r6 lesson (rule #20): vals[..][ph+a] with runtime ph demoted vals to
// scratch (VGPR=44, 1088us). Fix: every register index is compile-time —
// runtime-uniform (s&1)/slot selected via unrolled-if guards.
// 512 threads (8 waves -> 256-VGPR budget): rb=t&31 owns rows 8rb+i;
// cg=t>>5 owns col-blocks cg and cg+16 (vals[2][8][8] = 128 regs).
// Panel s: pivots 4s..4s+3, pivot col-block pcb=s>>1, owner group pg=pcb&15,
// slot=pcb>>4, half=(s&1). U[a][i][rb] lane-consecutive LDS (conflict-free).
//   B = App^{-1} (4x4 in-register sweep, redundant; SPD Schur pivots >= 1)
//   E_j = B*N_j on the fly; generic vals[cc][i][j] -= M_i . E_j
//   row-fix (rb==pcb): vals[cc][ph+ii][j] = E_j[ii]
//   col-fix (cg==pg,cc==slot): vals[cc][i][ph+a] = M_i . B[:,a]
//   diag: vals[slot][ph+ii][ph+a] = -B[ii][a]
// sweep(all) = -G^{-1}; negate on store. Math identical to r6 (which PASSED).
// ---------------------------------------------------------------------------
__global__ __launch_bounds__(512) void sweep_blk512(const float* __restrict__ src,
                                                    float* __restrict__ dst) {
    __shared__ float U[4][8][32];   // [col-slot a][row-in-block i][rb] : 4 KB
    int t = threadIdx.x;
    int rb = t & 31;
    int cg = t >> 5;                // [0,16): owns col-blocks cg, cg+16
    float vals[2][8][8];
#pragma unroll
    for (int cc = 0; cc < 2; ++cc) {
        int cb = cg + 16 * cc;
#pragma unroll
        for (int i = 0; i < 8; ++i) {
            const float* row = &src[(8 * rb + i) * NMEAS + 8 * cb];
            float4 a = *(const float4*)row;
            float4 b = *(const float4*)(row + 4);
            vals[cc][i][0] = a.x; vals[cc][i][1] = a.y; vals[cc][i][2] = a.z; vals[cc][i][3] = a.w;
            vals[cc][i][4] = b.x; vals[cc][i][5] = b.y; vals[cc][i][6] = b.z; vals[cc][i][7] = b.w;
        }
    }

#pragma unroll 1
    for (int s = 0; s < 64; ++s) {
        int pcb  = s >> 1;          // pivot col-block [0,32)
        int pg   = pcb & 15;        // owning thread-group
        int slot = pcb >> 4;        // which cc of the owner
        int hsel = s & 1;           // which half (ph = hsel*4)
        __syncthreads();            // protect U from previous step's readers
        if (cg == pg) {             // publish pivot panel: U[a][i][rb]
#pragma unroll
            for (int cc = 0; cc < 2; ++cc) {
                if (cc != slot) continue;            // uniform cond, cc literal
#pragma unroll
                for (int hf = 0; hf < 2; ++hf) {
                    if (hf != hsel) continue;        // uniform cond, hf literal
#pragma unroll
                    for (int a = 0; a < 4; ++a)
#pragma unroll
                        for (int i = 0; i < 8; ++i)
                            U[a][i][rb] = vals[cc][i][hf * 4 + a];
                }
            }
        }
        __syncthreads();

        int ph = hsel * 4;          // runtime ph: ONLY used in LDS addressing
        // ---- B = App^{-1} via in-register 4x4 sweep (redundant per thread)
        float P[4][4];
#pragma unroll
        for (int a = 0; a < 4; ++a)
#pragma unroll
            for (int b = 0; b < 4; ++b)
                P[a][b] = U[b][ph + a][pcb];         // LDS read, uniform addr
#pragma unroll
        for (int p = 0; p < 4; ++p) {
            float inv = 1.0f / P[p][p];
            float rv[4], cv[4];
#pragma unroll
            for (int a = 0; a < 4; ++a) rv[a] = P[a][p];
#pragma unroll
            for (int b = 0; b < 4; ++b) cv[b] = P[p][b] * inv;
#pragma unroll
            for (int a = 0; a < 4; ++a)
#pragma unroll
                for (int b = 0; b < 4; ++b) P[a][b] -= rv[a] * cv[b];
#pragma unroll
            for (int b = 0; b < 4; ++b) P[p][b] = cv[b];
#pragma unroll
            for (int a = 0; a < 4; ++a) P[a][p] = rv[a] * inv;
            P[p][p] = -inv;
        }
        float B[4][4];              // P holds -App^{-1}
#pragma unroll
        for (int a = 0; a < 4; ++a)
#pragma unroll
            for (int b = 0; b < 4; ++b) B[a][b] = -P[a][b];

        // ---- M_i[a] = A[8rb+i][4s+a]  (pivot-panel rows for my rows)
        float M[8][4];
#pragma unroll
        for (int i = 0; i < 8; ++i)
#pragma unroll
            for (int a = 0; a < 4; ++a) M[i][a] = U[a][i][rb];

        // ---- generic rank-4 update + row-fix, E_j computed on the fly
#pragma unroll
        for (int cc = 0; cc < 2; ++cc) {
            int cb = cg + 16 * cc;
#pragma unroll
            for (int j = 0; j < 8; ++j) {
                float n0 = U[0][j][cb], n1 = U[1][j][cb],
                      n2 = U[2][j][cb], n3 = U[3][j][cb];
                float E[4];
#pragma unroll
                for (int a = 0; a < 4; ++a)
                    E[a] = B[a][0] * n0 + B[a][1] * n1 + B[a][2] * n2 + B[a][3] * n3;
#pragma unroll
                for (int i = 0; i < 8; ++i)
                    vals[cc][i][j] -= M[i][0] * E[0] + M[i][1] * E[1]
                                    + M[i][2] * E[2] + M[i][3] * E[3];
                if (rb == pcb) {    // pivot-row fixup: rows 4s..4s+3 -> E_j
#pragma unroll
                    for (int hf = 0; hf < 2; ++hf) {
                        if (hf != hsel) continue;
#pragma unroll
                        for (int ii = 0; ii < 4; ++ii)
                            vals[cc][hf * 4 + ii][j] = E[ii];
                    }
                }
            }
        }
        // ---- pivot-col fixup: cols 4s..4s+3 -> M_i . B[:,a]
        if (cg == pg) {
#pragma unroll
            for (int cc = 0; cc < 2; ++cc) {
                if (cc != slot) continue;
#pragma unroll
                for (int hf = 0; hf < 2; ++hf) {
                    if (hf != hsel) continue;
#pragma unroll
                    for (int i = 0; i < 8; ++i)
#pragma unroll
                        for (int a = 0; a < 4; ++a)
                            vals[cc][i][hf * 4 + a] =
                                M[i][0] * B[0][a] + M[i][1] * B[1][a]
                              + M[i][2] * B[2][a] + M[i][3] * B[3][a];
                }
            }
        }
        // ---- diagonal block: -App^{-1}  (must be last)
        if (rb == pcb && cg == pg) {
#pragma unroll
            for (int cc = 0; cc < 2; ++cc) {
                if (cc != slot) continue;
#pragma unroll
                for (int hf = 0; hf < 2; ++hf) {
                    if (hf != hsel) continue;
#pragma unroll
                    for (int ii = 0; ii < 4; ++ii)
#pragma unroll
                        for (int a = 0; a < 4; ++a)
                            vals[cc][hf * 4 + ii][hf * 4 + a] = -B[ii][a];
                }
            }
        }
    }
    // sweep(all) == -G^{-1}  ->  negate on store
#pragma unroll
    for (int cc = 0; cc < 2; ++cc) {
        int cb = cg + 16 * cc;
#pragma unroll
        for (int i = 0; i < 8; ++i)
#pragma unroll
            for (int j = 0; j < 8; ++j)
                dst[(8 * rb + i) * NMEAS + 8 * cb + j] = -vals[cc][i][j];
    }
}

// ---------------------------------------------------------------------------
// fp64 Newton refinement:  P = Gd @ X ;  Xn = 2X - X @ P   (X input fp32/fp64)
// (fp32 Newton was the r3/r4 bug: cancellation noise ~cond(G)*eps32)
// ---------------------------------------------------------------------------
template <typename TB>
__global__ __launch_bounds__(256) void mm_gd(const double* __restrict__ Gd,
                                             const TB* __restrict__ X,
                                             double* __restrict__ P) {
    __shared__ __align__(16) double row[NMEAS];
    int i = blockIdx.x;
    row[threadIdx.x] = Gd[i * NMEAS + threadIdx.x];
    __syncthreads();
    int j = threadIdx.x;
    double s = 0.0;
#pragma unroll 4
    for (int k = 0; k < NMEAS; ++k) s += row[k] * (double)X[k * NMEAS + j];
    P[i * NMEAS + j] = s;
}

template <typename TB>
__global__ __launch_bounds__(256) void upd_newton(const TB* __restrict__ X,
                                                  const double* __restrict__ P,
                                                  double* __restrict__ Xn) {
    __shared__ __align__(16) double row[NMEAS];
    int i = blockIdx.x;
    row[threadIdx.x] = (double)X[i * NMEAS + threadIdx.x];
    __syncthreads();
    int j = threadIdx.x;
    double s = 0.0;
#pragma unroll 4
    for (int k = 0; k < NMEAS; ++k) s += row[k] * P[k * NMEAS + j];
    Xn[i * NMEAS + j] = 2.0 * row[j] - s;
}

// ---------------------------------------------------------------------------
// K2: Hd = X2d @ A   (fp64 [256][256] @ fp32 [256][512] -> fp64 [256][512])
// ---------------------------------------------------------------------------
__global__ __launch_bounds__(256) void h_kernel_d(const double* __restrict__ Gi,
                                                  const float* __restrict__ A,
                                                  double* __restrict__ H) {
    __shared__ __align__(16) double grow[NMEAS];
    int i = blockIdx.x;
    grow[threadIdx.x] = Gi[i * NMEAS + threadIdx.x];
    __syncthreads();
    int k0 = threadIdx.x;
    double s0 = 0.0, s1 = 0.0;
#pragma unroll 4
    for (int j = 0; j < NMEAS; ++j) {
        double g = grow[j];
        s0 += g * (double)A[j * NATOMS + k0];
        s1 += g * (double)A[j * NATOMS + k0 + 256];
    }
    H[i * NATOMS + k0] = s0;
    H[i * NATOMS + k0 + 256] = s1;
}

// ---------------------------------------------------------------------------
// K3: W = I - A^T @ Hd  (fp64 accumulate), stored as bf16 hi/lo split
// ---------------------------------------------------------------------------
__global__ __launch_bounds__(256) void w_kernel_d(const float* __restrict__ A,
                                                  const double* __restrict__ H,
                                                  unsigned short* __restrict__ Whg,
                                                  unsigned short* __restrict__ Wlg) {
    __shared__ __align__(16) double acol[NMEAS];
    int p = blockIdx.x;
    acol[threadIdx.x] = (double)A[threadIdx.x * NATOMS + p];
    __syncthreads();
    int q0 = threadIdx.x;
    double s0 = 0.0, s1 = 0.0;
#pragma unroll 4
    for (int m = 0; m < NMEAS; ++m) {
        double a = acol[m];
        s0 += a * H[m * NATOMS + q0];
        s1 += a * H[m * NATOMS + q0 + 256];
    }
    double w0 = ((p == q0)       ? 1.0 : 0.0) - s0;
    double w1 = ((p == q0 + 256) ? 1.0 : 0.0) - s1;
    unsigned short h0 = f2bf((float)w0), h1 = f2bf((float)w1);
    Whg[p * NATOMS + q0]       = h0;
    Wlg[p * NATOMS + q0]       = f2bf((float)(w0 - (double)bf2f(h0)));
    Whg[p * NATOMS + q0 + 256] = h1;
    Wlg[p * NATOMS + q0 + 256] = f2bf((float)(w1 - (double)bf2f(h1)));
}

// ---------------------------------------------------------------------------
// K4: Delta0 = AtY (= t_1, since t_0 = 0), stored split bf16 hi/lo,
//     TRANSPOSED to [4096 voxels][512 atoms] for k-contiguous staging.
// AtY[k][b] = sum_m A[m][k] * Y[b][m]
// ---------------------------------------------------------------------------
__global__ __launch_bounds__(256) void aty_kernel(const float* __restrict__ A,
                                                  const float* __restrict__ Y,
                                                  unsigned short* __restrict__ Dh0,
                                                  unsigned short* __restrict__ Dl0) {
    __shared__ __align__(16) float At[64][65];
    __shared__ __align__(16) float Yt[64][65];
    int b0 = blockIdx.x * 64, k0 = blockIdx.y * 64;
    int t = threadIdx.x, tx = t & 15, ty = t >> 4;
    float acc[4][4] = {};
    for (int m0 = 0; m0 < NMEAS; m0 += 64) {
        __syncthreads();
        {
            int kk = t & 63, mr = t >> 6;
#pragma unroll
            for (int p = 0; p < 16; ++p)
                At[mr + 4 * p][kk] = A[(m0 + mr + 4 * p) * NATOMS + k0 + kk];
            int mm = t & 63, br = t >> 6;
#pragma unroll
            for (int p = 0; p < 16; ++p)
                Yt[mm][br + 4 * p] = Y[(b0 + br + 4 * p) * NMEAS + m0 + mm];
        }
        __syncthreads();
#pragma unroll 4
        for (int m = 0; m < 64; ++m) {
            float av[4], yv[4];
#pragma unroll
            for (int i = 0; i < 4; ++i) av[i] = At[m][ty * 4 + i];
#pragma unroll
            for (int j = 0; j < 4; ++j) yv[j] = Yt[m][tx * 4 + j];
#pragma unroll
            for (int i = 0; i < 4; ++i)
#pragma unroll
                for (int j = 0; j < 4; ++j) acc[i][j] += av[i] * yv[j];
        }
    }
#pragma unroll
    for (int j = 0; j < 4; ++j) {
        int b = b0 + tx * 4 + j;
        s4v h4, l4;
#pragma unroll
        for (int i = 0; i < 4; ++i) {
            float f = acc[i][j];
            unsigned short h = f2bf(f);
            h4[i] = (short)h;
            l4[i] = (short)f2bf(f - bf2f(h));
        }
        *(s4v*)&Dh0[(long)b * NATOMS + k0 + ty * 4] = h4;
        *(s4v*)&Dl0[(long)b * NATOMS + k0 + ty * 4] = l4;
    }
}

// ---------------------------------------------------------------------------
// K5: one ADMM iteration, DELTA form, bf16-split MFMA, 3 terms
//   (Wh*Dh + Wh*Dl + Wl*Dh; dropped Wl*Dl <= 2^-18 rel):
//   dx = W @ Delta_in ; x_k = x_{k-1}+dx ; v_k = x_k + min(v_{k-1},0.1)
//   Delta_out = g(v_k)-g(v_{k-1}) -> split bf16 transposed [n][k]
// LAST: out[b][k] = x_{k-1} + dx  (transposed fp32 write)
// Tile: BM=64 x BN=128, BK=32, 256 thr (4 waves), mfma_f32_16x16x32_bf16.
// T1 XCD swizzle: XCD k gets bx in [4k,4k+4) x all by -> per-XCD L2
// footprint = 4 D-tiles (1MB) + 8 W-tiles (1MB) <= 4MB -> rereads hit L2.
// ---------------------------------------------------------------------------
template <int FIRST, int LAST>
__global__ __launch_bounds__(256) void admm_delta(
        const unsigned short* __restrict__ Whg,
        const unsigned short* __restrict__ Wlg,
        const unsigned short* __restrict__ Dhg,
        const unsigned short* __restrict__ Dlg,
        float* __restrict__ xbuf,            // fp32 x [512][4096], in-place
        float* __restrict__ vbuf,            // fp32 v [512][4096], in-place (d_out)
        unsigned short* __restrict__ DhOut,
        unsigned short* __restrict__ DlOut,
        float* __restrict__ out) {
    __shared__ __align__(16) char smem[61440];
    unsigned short* Whs = (unsigned short*)smem;      // [2][64*40]
    unsigned short* Wls = Whs + 2 * 64 * 40;          // [2][64*40]
    unsigned short* Dhs = Wls + 2 * 64 * 40;          // [2][128*40]
    unsigned short* Dls = Dhs + 2 * 128 * 40;         // [2][128*40]

    const int t = threadIdx.x;
    const int lane = t & 63, wv = t >> 6;
    const int ln = lane & 15, kg = lane >> 4;

    // XCD-aware bijective swizzle (grid 256 = 32x8, 8 XCDs, 32 blocks each)
    int bid = blockIdx.x + (blockIdx.y << 5);
    int xr = bid & 7, q = bid >> 3;
    int bx = xr * 4 + (q >> 3);          // [0,32)
    int by = q & 7;                      // [0,8)
    const int n0 = bx * 128, m0 = by * 64;

    const int wm = t >> 2, wslot = t & 3;
    const int tn = t >> 2, tslot = t & 3;

    f32x4 acc[4][2] = {};
    s8v rwh, rwl, rth0, rth1, rtl0, rtl1;

#define GLOAD(kc)                                                                \
    {                                                                            \
        long ko = (long)(kc)*32;                                                 \
        rwh  = *(const s8v*)&Whg[(long)(m0 + wm) * NATOMS + ko + wslot * 8];     \
        rwl  = *(const s8v*)&Wlg[(long)(m0 + wm) * NATOMS + ko + wslot * 8];     \
        rth0 = *(const s8v*)&Dhg[(long)(n0 + tn) * NATOMS + ko + tslot * 8];     \
        rth1 = *(const s8v*)&Dhg[(long)(n0 + 64 + tn) * NATOMS + ko + tslot * 8];\
        rtl0 = *(const s8v*)&Dlg[(long)(n0 + tn) * NATOMS + ko + tslot * 8];     \
        rtl1 = *(const s8v*)&Dlg[(long)(n0 + 64 + tn) * NATOMS + ko + tslot * 8];\
    }
#define DSWRITE(b)                                                  \
    {                                                               \
        *(s8v*)&Whs[(b)*2560 + wm * 40 + wslot * 8] = rwh;          \
        *(s8v*)&Wls[(b)*2560 + wm * 40 + wslot * 8] = rwl;          \
        *(s8v*)&Dhs[(b)*5120 + tn * 40 + tslot * 8] = rth0;         \
        *(s8v*)&Dhs[(b)*5120 + (64 + tn) * 40 + tslot * 8] = rth1;  \
        *(s8v*)&Dls[(b)*5120 + tn * 40 + tslot * 8] = rtl0;         \
        *(s8v*)&Dls[(b)*5120 + (64 + tn) * 40 + tslot * 8] = rtl1;  \
    }

    GLOAD(0);
    DSWRITE(0);
#pragma unroll 1
    for (int c = 0; c < 16; ++c) {
        if (c < 15) GLOAD(c + 1);
        __syncthreads();
        const int b = c & 1;
        const unsigned short* wh = &Whs[b * 2560];
        const unsigned short* wl = &Wls[b * 2560];
        const unsigned short* dh = &Dhs[b * 5120];
        const unsigned short* dl = &Dls[b * 5120];
        s8v ah[4], al[4], bh[2], bl[2];
#pragma unroll
        for (int mi = 0; mi < 4; ++mi) {
            ah[mi] = *(const s8v*)&wh[(mi * 16 + ln) * 40 + kg * 8];
            al[mi] = *(const s8v*)&wl[(mi * 16 + ln) * 40 + kg * 8];
        }
#pragma unroll
        for (int ni = 0; ni < 2; ++ni) {
            int r = wv * 32 + ni * 16 + ln;
            bh[ni] = *(const s8v*)&dh[r * 40 + kg * 8];
            bl[ni] = *(const s8v*)&dl[r * 40 + kg * 8];
        }
#pragma unroll
        for (int mi = 0; mi < 4; ++mi)
#pragma unroll
            for (int ni = 0; ni < 2; ++ni) {
                acc[mi][ni] = __builtin_amdgcn_mfma_f32_16x16x32_bf16(ah[mi], bh[ni], acc[mi][ni], 0, 0, 0);
                acc[mi][ni] = __builtin_amdgcn_mfma_f32_16x16x32_bf16(ah[mi], bl[ni], acc[mi][ni], 0, 0, 0);
                acc[mi][ni] = __builtin_amdgcn_mfma_f32_16x16x32_bf16(al[mi], bh[ni], acc[mi][ni], 0, 0, 0);
            }
        if (c < 15) DSWRITE((c + 1) & 1);
    }
#undef GLOAD
#undef DSWRITE

    __syncthreads();                        // staging LDS dead; reuse as xT [128][68] f32
    float* xT = (float*)smem;

    if (!LAST) {
#pragma unroll
        for (int mi = 0; mi < 4; ++mi)
#pragma unroll
            for (int ni = 0; ni < 2; ++ni) {
                int nn = n0 + wv * 32 + ni * 16 + ln;
                f32x4 dlt;
#pragma unroll
                for (int j = 0; j < 4; ++j) {
                    int m = m0 + mi * 16 + kg * 4 + j;
                    long idx = (long)m * NVOX + nn;
                    float dx = acc[mi][ni][j];
                    float xn, vn, gold;
                    if (FIRST) {
                        xn = dx; vn = xn; gold = 0.0f;   // x0=0, u0=0, v0=0
                    } else {
                        xn = xbuf[idx] + dx;
                        float vp = vbuf[idx];
                        vn = xn + fminf(vp, 0.1f);
                        gold = g_of(vp);
                    }
                    xbuf[idx] = xn;
                    vbuf[idx] = vn;
                    dlt[j] = g_of(vn) - gold;
                }
                int nl = wv * 32 + ni * 16 + ln;
                int ml = mi * 16 + kg * 4;
                *(f32x4*)&xT[nl * 68 + ml] = dlt;
            }
        __syncthreads();
        int nl = t >> 1, seg = t & 1;
#pragma unroll
        for (int q8 = 0; q8 < 4; ++q8) {
            s8v hv, lv;
#pragma unroll
            for (int e = 0; e < 8; ++e) {
                float f = xT[nl * 68 + seg * 32 + q8 * 8 + e];
                unsigned short h = f2bf(f);
                hv[e] = (short)h;
                lv[e] = (short)f2bf(f - bf2f(h));
            }
            *(s8v*)&DhOut[(long)(n0 + nl) * NATOMS + m0 + seg * 32 + q8 * 8] = hv;
            *(s8v*)&DlOut[(long)(n0 + nl) * NATOMS + m0 + seg * 32 + q8 * 8] = lv;
        }
    } else {
        // LAST: out[b][k] = x_{k-1}[k][b] + dx  (transposed fp32 write)
#pragma unroll
        for (int mi = 0; mi < 4; ++mi)
#pragma unroll
            for (int ni = 0; ni < 2; ++ni) {
                int nn = n0 + wv * 32 + ni * 16 + ln;
                f32x4 tv;
#pragma unroll
                for (int j = 0; j < 4; ++j) {
                    int m = m0 + mi * 16 + kg * 4 + j;
                    tv[j] = xbuf[(long)m * NVOX + nn] + acc[mi][ni][j];
                }
                int nl = wv * 32 + ni * 16 + ln;
                int ml = mi * 16 + kg * 4;
                *(f32x4*)&xT[nl * 68 + ml] = tv;
            }
        __syncthreads();
        int nl = t >> 1, seg = t & 1;
#pragma unroll
        for (int q = 0; q < 8; ++q) {
            f32x4 v = *(const f32x4*)&xT[nl * 68 + seg * 32 + q * 4];
            *(f32x4*)&out[(long)(n0 + nl) * NATOMS + m0 + seg * 32 + q * 4] = v;
        }
    }
}

// ---------------------------------------------------------------------------
extern "C" void kernel_launch(void* const* d_in, const int* in_sizes, int n_in,
                              void* d_out, int out_size, void* d_ws, size_t ws_size,
                              hipStream_t stream) {
    const float* Y = (const float*)d_in[0];   // [4096][256]
    const float* A = (const float*)d_in[1];   // [256][512]

    // ws layout (float units), lifetime-checked overlays; total 6946816 floats
    // = 26.5 MiB (r3-r6 proven footprint).
    float* ws = (float*)d_ws;
    double* Gd  = (double*)(ws + 0);        // [0,131072)       dead after step 5
    float*  Gf  = ws + 131072;              // [131072,196608)  dead after sweep
    float*  X0f = ws + 196608;              // [196608,262144)  dead after step 4
    double* X1d = (double*)(ws + 262144);   // [262144,393216)  dead after step 6
    double* Pd  = (double*)(ws + 393216);   // [393216,524288)  dead after step 6
    double* X2d = (double*)(ws + 131072);   // overlays Gf+X0f (both dead)
    double* Hd  = (double*)(ws + 393216);   // [393216,655360) overlays Pd (dead)
    float*  xbuf = ws + 655360;             // [655360,2752512) fp32 x state
    unsigned short* Whg = (unsigned short*)(ws + 0);        // overlays Gd (dead)
    unsigned short* Wlg = (unsigned short*)(ws + 131072);   // overlays X2d (dead after h)
    unsigned short* DAh = (unsigned short*)(ws + 2752512);
    unsigned short* DAl = (unsigned short*)(ws + 3801088);
    unsigned short* DBh = (unsigned short*)(ws + 4849664);
    unsigned short* DBl = (unsigned short*)(ws + 5898240);  // end 6946816
    float* vbuf = (float*)d_out;   // v_k fp32, iters 1..29 (d_out as scratch)
    float* outp = (float*)d_out;   // final output, written by LAST iter only

    g_kernel_d<<<256, 256, 0, stream>>>(A, Gd, Gf);                 // 1
    sweep_blk512<<<1, 512, 0, stream>>>(Gf, X0f);                   // 2
    mm_gd<float><<<256, 256, 0, stream>>>(Gd, X0f, Pd);             // 3
    upd_newton<float><<<256, 256, 0, stream>>>(X0f, Pd, X1d);       // 4
    mm_gd<double><<<256, 256, 0, stream>>>(Gd, X1d, Pd);            // 5
    upd_newton<double><<<256, 256, 0, stream>>>(X1d, Pd, X2d);      // 6
    h_kernel_d<<<256, 256, 0, stream>>>(X2d, A, Hd);                // 7
    w_kernel_d<<<512, 256, 0, stream>>>(A, Hd, Whg, Wlg);           // 8
    aty_kernel<<<dim3(64, 8), 256, 0, stream>>>(A, Y, DAh, DAl);    // 9

    dim3 ig(NVOX / 128, NATOMS / 64);  // (32, 8) = 256 blocks
    unsigned short *ch = DAh, *cl = DAl, *nh = DBh, *nl = DBl;
    // iter 1: Delta_0 = AtY; x1 = W*AtY; v1 = x1; Delta_1 = g(v1)
    admm_delta<1, 0><<<ig, 256, 0, stream>>>(Whg, Wlg, ch, cl, xbuf, vbuf, nh, nl, nullptr);
    { unsigned short* s; s = ch; ch = nh; nh = s; s = cl; cl = nl; nl = s; }
    for (int it = 2; it <= NITER - 1; ++it) {
        admm_delta<0, 0><<<ig, 256, 0, stream>>>(Whg, Wlg, ch, cl, xbuf, vbuf, nh, nl, nullptr);
        unsigned short* s; s = ch; ch = nh; nh = s; s = cl; cl = nl; nl = s;
    }
    // iter 30: x30 = x29 + W*Delta_29, written transposed to d_out
    admm_delta<0, 1><<<ig, 256, 0, stream>>>(Whg, Wlg, ch, cl, xbuf, vbuf, nullptr, nullptr, outp);
}

// Round 8
// 1095.614 us; speedup vs baseline: 1.7540x; 1.0005x over previous
//
#include <hip/hip_runtime.h>

// Problem constants (from reference setup_inputs)
#define NVOX   4096   // B voxels
#define NMEAS  256    // M measurements
#define NATOMS 512    // K atoms
#define NITER  30

typedef __attribute__((ext_vector_type(8))) short s8v;   // 8 bf16 (4 VGPR) MFMA frag
typedef __attribute__((ext_vector_type(4))) short s4v;
typedef __attribute__((ext_vector_type(4))) float f32x4;

// bf16 round-to-nearest-even split helpers (no NaN/Inf in this problem)
__device__ __forceinline__ unsigned short f2bf(float x) {
    unsigned u = __builtin_bit_cast(unsigned, x);
    u += 0x7fff + ((u >> 16) & 1);
    return (unsigned short)(u >> 16);
}
__device__ __forceinline__ float bf2f(unsigned short b) {
    unsigned u = ((unsigned)b) << 16;
    return __builtin_bit_cast(float, u);
}
// g(v) = (z - u) collapsed through v = x + u :  relu(v-0.1) - min(v,0.1)
__device__ __forceinline__ float g_of(float v) {
    return fmaxf(v - 0.1f, 0.0f) - fminf(v, 0.1f);
}

// ---------------------------------------------------------------------------
// K0: G = I + A*A^T in fp64 (Gd) + fp32 copy (Gf) for the sweep
// ---------------------------------------------------------------------------
__global__ __launch_bounds__(256) void g_kernel_d(const float* __restrict__ A,
                                                  double* __restrict__ Gd,
                                                  float* __restrict__ Gf) {
    __shared__ float arow[NATOMS];
    int i = blockIdx.x;
    for (int k = threadIdx.x; k < NATOMS; k += 256) arow[k] = A[i * NATOMS + k];
    __syncthreads();
    int j = threadIdx.x;
    const float* aj = A + j * NATOMS;
    double s = (i == j) ? 1.0 : 0.0;
#pragma unroll 4
    for (int k = 0; k < NATOMS; ++k) s += (double)arow[k] * (double)aj[k];
    Gd[i * NMEAS + j] = s;
    Gf[i * NMEAS + j] = (float)s;
}

// ---------------------------------------------------------------------------
// K1: SPD inverse of Gf (256x256), BLOCKED symmetric SWEEP, panel NB=4.
// r7 lesson: __launch_bounds__(512) alone let the allocator cap at 128 VGPR
// (4 waves/EU heuristic) and SPILL the 210-reg working set (vals[2][8][8]=128
// + M 32 + B/P 32) -> 410us of scratch latency. Fix: (512, 2) = min 2
// waves/EU -> 256-VGPR budget, no spill. An 8-wave block is exactly 2
// waves/EU, so occupancy is unchanged; math is bit-identical to r7 (PASSED).
// All register indexing compile-time (rule #20): runtime-uniform slot/half
// selected via unrolled-if guards; runtime ph used only in LDS addressing.
// sweep(all) = -G^{-1}; negate on store.
// ---------------------------------------------------------------------------
__global__ __launch_bounds__(512, 2) void sweep_blk512(const float* __restrict__ src,
                                                       float* __restrict__ dst) {
    __shared__ float U[4][8][32];   // [col-slot a][row-in-block i][rb] : 4 KB
    int t = threadIdx.x;
    int rb = t & 31;
    int cg = t >> 5;                // [0,16): owns col-blocks cg, cg+16
    float vals[2][8][8];
#pragma unroll
    for (int cc = 0; cc < 2; ++cc) {
        int cb = cg + 16 * cc;
#pragma unroll
        for (int i = 0; i < 8; ++i) {
            const float* row = &src[(8 * rb + i) * NMEAS + 8 * cb];
            float4 a = *(const float4*)row;
            float4 b = *(const float4*)(row + 4);
            vals[cc][i][0] = a.x; vals[cc][i][1] = a.y; vals[cc][i][2] = a.z; vals[cc][i][3] = a.w;
            vals[cc][i][4] = b.x; vals[cc][i][5] = b.y; vals[cc][i][6] = b.z; vals[cc][i][7] = b.w;
        }
    }

#pragma unroll 1
    for (int s = 0; s < 64; ++s) {
        int pcb  = s >> 1;          // pivot col-block [0,32)
        int pg   = pcb & 15;        // owning thread-group
        int slot = pcb >> 4;        // which cc of the owner
        int hsel = s & 1;           // which half (ph = hsel*4)
        __syncthreads();            // protect U from previous step's readers
        if (cg == pg) {             // publish pivot panel: U[a][i][rb]
#pragma unroll
            for (int cc = 0; cc < 2; ++cc) {
                if (cc != slot) continue;            // uniform cond, cc literal
#pragma unroll
                for (int hf = 0; hf < 2; ++hf) {
                    if (hf != hsel) continue;        // uniform cond, hf literal
#pragma unroll
                    for (int a = 0; a < 4; ++a)
#pragma unroll
                        for (int i = 0; i < 8; ++i)
                            U[a][i][rb] = vals[cc][i][hf * 4 + a];
                }
            }
        }
        __syncthreads();

        int ph = hsel * 4;          // runtime ph: ONLY used in LDS addressing
        // ---- B = App^{-1} via in-register 4x4 sweep (redundant per thread)
        float P[4][4];
#pragma unroll
        for (int a = 0; a < 4; ++a)
#pragma unroll
            for (int b = 0; b < 4; ++b)
                P[a][b] = U[b][ph + a][pcb];         // LDS read, uniform addr
#pragma unroll
        for (int p = 0; p < 4; ++p) {
            float inv = 1.0f / P[p][p];
            float rv[4], cv[4];
#pragma unroll
            for (int a = 0; a < 4; ++a) rv[a] = P[a][p];
#pragma unroll
            for (int b = 0; b < 4; ++b) cv[b] = P[p][b] * inv;
#pragma unroll
            for (int a = 0; a < 4; ++a)
#pragma unroll
                for (int b = 0; b < 4; ++b) P[a][b] -= rv[a] * cv[b];
#pragma unroll
            for (int b = 0; b < 4; ++b) P[p][b] = cv[b];
#pragma unroll
            for (int a = 0; a < 4; ++a) P[a][p] = rv[a] * inv;
            P[p][p] = -inv;
        }
        float B[4][4];              // P holds -App^{-1}
#pragma unroll
        for (int a = 0; a < 4; ++a)
#pragma unroll
            for (int b = 0; b < 4; ++b) B[a][b] = -P[a][b];

        // ---- M_i[a] = A[8rb+i][4s+a]  (pivot-panel rows for my rows)
        float M[8][4];
#pragma unroll
        for (int i = 0; i < 8; ++i)
#pragma unroll
            for (int a = 0; a < 4; ++a) M[i][a] = U[a][i][rb];

        // ---- generic rank-4 update + row-fix, E_j computed on the fly
#pragma unroll
        for (int cc = 0; cc < 2; ++cc) {
            int cb = cg + 16 * cc;
#pragma unroll
            for (int j = 0; j < 8; ++j) {
                float n0 = U[0][j][cb], n1 = U[1][j][cb],
                      n2 = U[2][j][cb], n3 = U[3][j][cb];
                float E[4];
#pragma unroll
                for (int a = 0; a < 4; ++a)
                    E[a] = B[a][0] * n0 + B[a][1] * n1 + B[a][2] * n2 + B[a][3] * n3;
#pragma unroll
                for (int i = 0; i < 8; ++i)
                    vals[cc][i][j] -= M[i][0] * E[0] + M[i][1] * E[1]
                                    + M[i][2] * E[2] + M[i][3] * E[3];
                if (rb == pcb) {    // pivot-row fixup: rows 4s..4s+3 -> E_j
#pragma unroll
                    for (int hf = 0; hf < 2; ++hf) {
                        if (hf != hsel) continue;
#pragma unroll
                        for (int ii = 0; ii < 4; ++ii)
                            vals[cc][hf * 4 + ii][j] = E[ii];
                    }
                }
            }
        }
        // ---- pivot-col fixup: cols 4s..4s+3 -> M_i . B[:,a]
        if (cg == pg) {
#pragma unroll
            for (int cc = 0; cc < 2; ++cc) {
                if (cc != slot) continue;
#pragma unroll
                for (int hf = 0; hf < 2; ++hf) {
                    if (hf != hsel) continue;
#pragma unroll
                    for (int i = 0; i < 8; ++i)
#pragma unroll
                        for (int a = 0; a < 4; ++a)
                            vals[cc][i][hf * 4 + a] =
                                M[i][0] * B[0][a] + M[i][1] * B[1][a]
                              + M[i][2] * B[2][a] + M[i][3] * B[3][a];
                }
            }
        }
        // ---- diagonal block: -App^{-1}  (must be last)
        if (rb == pcb && cg == pg) {
#pragma unroll
            for (int cc = 0; cc < 2; ++cc) {
                if (cc != slot) continue;
#pragma unroll
                for (int hf = 0; hf < 2; ++hf) {
                    if (hf != hsel) continue;
#pragma unroll
                    for (int ii = 0; ii < 4; ++ii)
#pragma unroll
                        for (int a = 0; a < 4; ++a)
                            vals[cc][hf * 4 + ii][hf * 4 + a] = -B[ii][a];
                }
            }
        }
    }
    // sweep(all) == -G^{-1}  ->  negate on store
#pragma unroll
    for (int cc = 0; cc < 2; ++cc) {
        int cb = cg + 16 * cc;
#pragma unroll
        for (int i = 0; i < 8; ++i)
#pragma unroll
            for (int j = 0; j < 8; ++j)
                dst[(8 * rb + i) * NMEAS + 8 * cb + j] = -vals[cc][i][j];
    }
}

// ---------------------------------------------------------------------------
// fp64 Newton refinement:  P = Gd @ X ;  Xn = 2X - X @ P   (X input fp32/fp64)
// (fp32 Newton was the r3/r4 bug: cancellation noise ~cond(G)*eps32)
// ---------------------------------------------------------------------------
template <typename TB>
__global__ __launch_bounds__(256) void mm_gd(const double* __restrict__ Gd,
                                             const TB* __restrict__ X,
                                             double* __restrict__ P) {
    __shared__ __align__(16) double row[NMEAS];
    int i = blockIdx.x;
    row[threadIdx.x] = Gd[i * NMEAS + threadIdx.x];
    __syncthreads();
    int j = threadIdx.x;
    double s = 0.0;
#pragma unroll 4
    for (int k = 0; k < NMEAS; ++k) s += row[k] * (double)X[k * NMEAS + j];
    P[i * NMEAS + j] = s;
}

template <typename TB>
__global__ __launch_bounds__(256) void upd_newton(const TB* __restrict__ X,
                                                  const double* __restrict__ P,
                                                  double* __restrict__ Xn) {
    __shared__ __align__(16) double row[NMEAS];
    int i = blockIdx.x;
    row[threadIdx.x] = (double)X[i * NMEAS + threadIdx.x];
    __syncthreads();
    int j = threadIdx.x;
    double s = 0.0;
#pragma unroll 4
    for (int k = 0; k < NMEAS; ++k) s += row[k] * P[k * NMEAS + j];
    Xn[i * NMEAS + j] = 2.0 * row[j] - s;
}

// ---------------------------------------------------------------------------
// K2: Hd = X2d @ A   (fp64 [256][256] @ fp32 [256][512] -> fp64 [256][512])
// ---------------------------------------------------------------------------
__global__ __launch_bounds__(256) void h_kernel_d(const double* __restrict__ Gi,
                                                  const float* __restrict__ A,
                                                  double* __restrict__ H) {
    __shared__ __align__(16) double grow[NMEAS];
    int i = blockIdx.x;
    grow[threadIdx.x] = Gi[i * NMEAS + threadIdx.x];
    __syncthreads();
    int k0 = threadIdx.x;
    double s0 = 0.0, s1 = 0.0;
#pragma unroll 4
    for (int j = 0; j < NMEAS; ++j) {
        double g = grow[j];
        s0 += g * (double)A[j * NATOMS + k0];
        s1 += g * (double)A[j * NATOMS + k0 + 256];
    }
    H[i * NATOMS + k0] = s0;
    H[i * NATOMS + k0 + 256] = s1;
}

// ---------------------------------------------------------------------------
// K3: W = I - A^T @ Hd  (fp64 accumulate), stored as bf16 hi/lo split
// ---------------------------------------------------------------------------
__global__ __launch_bounds__(256) void w_kernel_d(const float* __restrict__ A,
                                                  const double* __restrict__ H,
                                                  unsigned short* __restrict__ Whg,
                                                  unsigned short* __restrict__ Wlg) {
    __shared__ __align__(16) double acol[NMEAS];
    int p = blockIdx.x;
    acol[threadIdx.x] = (double)A[threadIdx.x * NATOMS + p];
    __syncthreads();
    int q0 = threadIdx.x;
    double s0 = 0.0, s1 = 0.0;
#pragma unroll 4
    for (int m = 0; m < NMEAS; ++m) {
        double a = acol[m];
        s0 += a * H[m * NATOMS + q0];
        s1 += a * H[m * NATOMS + q0 + 256];
    }
    double w0 = ((p == q0)       ? 1.0 : 0.0) - s0;
    double w1 = ((p == q0 + 256) ? 1.0 : 0.0) - s1;
    unsigned short h0 = f2bf((float)w0), h1 = f2bf((float)w1);
    Whg[p * NATOMS + q0]       = h0;
    Wlg[p * NATOMS + q0]       = f2bf((float)(w0 - (double)bf2f(h0)));
    Whg[p * NATOMS + q0 + 256] = h1;
    Wlg[p * NATOMS + q0 + 256] = f2bf((float)(w1 - (double)bf2f(h1)));
}

// ---------------------------------------------------------------------------
// K4: Delta0 = AtY (= t_1, since t_0 = 0), stored split bf16 hi/lo,
//     TRANSPOSED to [4096 voxels][512 atoms] for k-contiguous staging.
// AtY[k][b] = sum_m A[m][k] * Y[b][m]
// ---------------------------------------------------------------------------
__global__ __launch_bounds__(256) void aty_kernel(const float* __restrict__ A,
                                                  const float* __restrict__ Y,
                                                  unsigned short* __restrict__ Dh0,
                                                  unsigned short* __restrict__ Dl0) {
    __shared__ __align__(16) float At[64][65];
    __shared__ __align__(16) float Yt[64][65];
    int b0 = blockIdx.x * 64, k0 = blockIdx.y * 64;
    int t = threadIdx.x, tx = t & 15, ty = t >> 4;
    float acc[4][4] = {};
    for (int m0 = 0; m0 < NMEAS; m0 += 64) {
        __syncthreads();
        {
            int kk = t & 63, mr = t >> 6;
#pragma unroll
            for (int p = 0; p < 16; ++p)
                At[mr + 4 * p][kk] = A[(m0 + mr + 4 * p) * NATOMS + k0 + kk];
            int mm = t & 63, br = t >> 6;
#pragma unroll
            for (int p = 0; p < 16; ++p)
                Yt[mm][br + 4 * p] = Y[(b0 + br + 4 * p) * NMEAS + m0 + mm];
        }
        __syncthreads();
#pragma unroll 4
        for (int m = 0; m < 64; ++m) {
            float av[4], yv[4];
#pragma unroll
            for (int i = 0; i < 4; ++i) av[i] = At[m][ty * 4 + i];
#pragma unroll
            for (int j = 0; j < 4; ++j) yv[j] = Yt[m][tx * 4 + j];
#pragma unroll
            for (int i = 0; i < 4; ++i)
#pragma unroll
                for (int j = 0; j < 4; ++j) acc[i][j] += av[i] * yv[j];
        }
    }
#pragma unroll
    for (int j = 0; j < 4; ++j) {
        int b = b0 + tx * 4 + j;
        s4v h4, l4;
#pragma unroll
        for (int i = 0; i < 4; ++i) {
            float f = acc[i][j];
            unsigned short h = f2bf(f);
            h4[i] = (short)h;
            l4[i] = (short)f2bf(f - bf2f(h));
        }
        *(s4v*)&Dh0[(long)b * NATOMS + k0 + ty * 4] = h4;
        *(s4v*)&Dl0[(long)b * NATOMS + k0 + ty * 4] = l4;
    }
}

// ---------------------------------------------------------------------------
// K5: one ADMM iteration, DELTA form, bf16-split MFMA, 3 terms
//   (Wh*Dh + Wh*Dl + Wl*Dh; dropped Wl*Dl <= 2^-18 rel):
//   dx = W @ Delta_in ; x_k = x_{k-1}+dx ; v_k = x_k + min(v_{k-1},0.1)
//   Delta_out = g(v_k)-g(v_{k-1}) -> split bf16 transposed [n][k]
// LAST: out[b][k] = x_{k-1} + dx  (transposed fp32 write)
// Tile: BM=64 x BN=128, BK=32, 256 thr (4 waves), mfma_f32_16x16x32_bf16.
// T1 XCD swizzle: XCD k gets bx in [4k,4k+4) x all by -> per-XCD L2
// footprint = 4 D-tiles (1MB) + 8 W-tiles (1MB) <= 4MB -> rereads hit L2.
// ---------------------------------------------------------------------------
template <int FIRST, int LAST>
__global__ __launch_bounds__(256) void admm_delta(
        const unsigned short* __restrict__ Whg,
        const unsigned short* __restrict__ Wlg,
        const unsigned short* __restrict__ Dhg,
        const unsigned short* __restrict__ Dlg,
        float* __restrict__ xbuf,            // fp32 x [512][4096], in-place
        float* __restrict__ vbuf,            // fp32 v [512][4096], in-place (d_out)
        unsigned short* __restrict__ DhOut,
        unsigned short* __restrict__ DlOut,
        float* __restrict__ out) {
    __shared__ __align__(16) char smem[61440];
    unsigned short* Whs = (unsigned short*)smem;      // [2][64*40]
    unsigned short* Wls = Whs + 2 * 64 * 40;          // [2][64*40]
    unsigned short* Dhs = Wls + 2 * 64 * 40;          // [2][128*40]
    unsigned short* Dls = Dhs + 2 * 128 * 40;         // [2][128*40]

    const int t = threadIdx.x;
    const int lane = t & 63, wv = t >> 6;
    const int ln = lane & 15, kg = lane >> 4;

    // XCD-aware bijective swizzle (grid 256 = 32x8, 8 XCDs, 32 blocks each)
    int bid = blockIdx.x + (blockIdx.y << 5);
    int xr = bid & 7, q = bid >> 3;
    int bx = xr * 4 + (q >> 3);          // [0,32)
    int by = q & 7;                      // [0,8)
    const int n0 = bx * 128, m0 = by * 64;

    const int wm = t >> 2, wslot = t & 3;
    const int tn = t >> 2, tslot = t & 3;

    f32x4 acc[4][2] = {};
    s8v rwh, rwl, rth0, rth1, rtl0, rtl1;

#define GLOAD(kc)                                                                \
    {                                                                            \
        long ko = (long)(kc)*32;                                                 \
        rwh  = *(const s8v*)&Whg[(long)(m0 + wm) * NATOMS + ko + wslot * 8];     \
        rwl  = *(const s8v*)&Wlg[(long)(m0 + wm) * NATOMS + ko + wslot * 8];     \
        rth0 = *(const s8v*)&Dhg[(long)(n0 + tn) * NATOMS + ko + tslot * 8];     \
        rth1 = *(const s8v*)&Dhg[(long)(n0 + 64 + tn) * NATOMS + ko + tslot * 8];\
        rtl0 = *(const s8v*)&Dlg[(long)(n0 + tn) * NATOMS + ko + tslot * 8];     \
        rtl1 = *(const s8v*)&Dlg[(long)(n0 + 64 + tn) * NATOMS + ko + tslot * 8];\
    }
#define DSWRITE(b)                                                  \
    {                                                               \
        *(s8v*)&Whs[(b)*2560 + wm * 40 + wslot * 8] = rwh;          \
        *(s8v*)&Wls[(b)*2560 + wm * 40 + wslot * 8] = rwl;          \
        *(s8v*)&Dhs[(b)*5120 + tn * 40 + tslot * 8] = rth0;         \
        *(s8v*)&Dhs[(b)*5120 + (64 + tn) * 40 + tslot * 8] = rth1;  \
        *(s8v*)&Dls[(b)*5120 + tn * 40 + tslot * 8] = rtl0;         \
        *(s8v*)&Dls[(b)*5120 + (64 + tn) * 40 + tslot * 8] = rtl1;  \
    }

    GLOAD(0);
    DSWRITE(0);
#pragma unroll 1
    for (int c = 0; c < 16; ++c) {
        if (c < 15) GLOAD(c + 1);
        __syncthreads();
        const int b = c & 1;
        const unsigned short* wh = &Whs[b * 2560];
        const unsigned short* wl = &Wls[b * 2560];
        const unsigned short* dh = &Dhs[b * 5120];
        const unsigned short* dl = &Dls[b * 5120];
        s8v ah[4], al[4], bh[2], bl[2];
#pragma unroll
        for (int mi = 0; mi < 4; ++mi) {
            ah[mi] = *(const s8v*)&wh[(mi * 16 + ln) * 40 + kg * 8];
            al[mi] = *(const s8v*)&wl[(mi * 16 + ln) * 40 + kg * 8];
        }
#pragma unroll
        for (int ni = 0; ni < 2; ++ni) {
            int r = wv * 32 + ni * 16 + ln;
            bh[ni] = *(const s8v*)&dh[r * 40 + kg * 8];
            bl[ni] = *(const s8v*)&dl[r * 40 + kg * 8];
        }
#pragma unroll
        for (int mi = 0; mi < 4; ++mi)
#pragma unroll
            for (int ni = 0; ni < 2; ++ni) {
                acc[mi][ni] = __builtin_amdgcn_mfma_f32_16x16x32_bf16(ah[mi], bh[ni], acc[mi][ni], 0, 0, 0);
                acc[mi][ni] = __builtin_amdgcn_mfma_f32_16x16x32_bf16(ah[mi], bl[ni], acc[mi][ni], 0, 0, 0);
                acc[mi][ni] = __builtin_amdgcn_mfma_f32_16x16x32_bf16(al[mi], bh[ni], acc[mi][ni], 0, 0, 0);
            }
        if (c < 15) DSWRITE((c + 1) & 1);
    }
#undef GLOAD
#undef DSWRITE

    __syncthreads();                        // staging LDS dead; reuse as xT [128][68] f32
    float* xT = (float*)smem;

    if (!LAST) {
#pragma unroll
        for (int mi = 0; mi < 4; ++mi)
#pragma unroll
            for (int ni = 0; ni < 2; ++ni) {
                int nn = n0 + wv * 32 + ni * 16 + ln;
                f32x4 dlt;
#pragma unroll
                for (int j = 0; j < 4; ++j) {
                    int m = m0 + mi * 16 + kg * 4 + j;
                    long idx = (long)m * NVOX + nn;
                    float dx = acc[mi][ni][j];
                    float xn, vn, gold;
                    if (FIRST) {
                        xn = dx; vn = xn; gold = 0.0f;   // x0=0, u0=0, v0=0
                    } else {
                        xn = xbuf[idx] + dx;
                        float vp = vbuf[idx];
                        vn = xn + fminf(vp, 0.1f);
                        gold = g_of(vp);
                    }
                    xbuf[idx] = xn;
                    vbuf[idx] = vn;
                    dlt[j] = g_of(vn) - gold;
                }
                int nl = wv * 32 + ni * 16 + ln;
                int ml = mi * 16 + kg * 4;
                *(f32x4*)&xT[nl * 68 + ml] = dlt;
            }
        __syncthreads();
        int nl = t >> 1, seg = t & 1;
#pragma unroll
        for (int q8 = 0; q8 < 4; ++q8) {
            s8v hv, lv;
#pragma unroll
            for (int e = 0; e < 8; ++e) {
                float f = xT[nl * 68 + seg * 32 + q8 * 8 + e];
                unsigned short h = f2bf(f);
                hv[e] = (short)h;
                lv[e] = (short)f2bf(f - bf2f(h));
            }
            *(s8v*)&DhOut[(long)(n0 + nl) * NATOMS + m0 + seg * 32 + q8 * 8] = hv;
            *(s8v*)&DlOut[(long)(n0 + nl) * NATOMS + m0 + seg * 32 + q8 * 8] = lv;
        }
    } else {
        // LAST: out[b][k] = x_{k-1}[k][b] + dx  (transposed fp32 write)
#pragma unroll
        for (int mi = 0; mi < 4; ++mi)
#pragma unroll
            for (int ni = 0; ni < 2; ++ni) {
                int nn = n0 + wv * 32 + ni * 16 + ln;
                f32x4 tv;
#pragma unroll
                for (int j = 0; j < 4; ++j) {
                    int m = m0 + mi * 16 + kg * 4 + j;
                    tv[j] = xbuf[(long)m * NVOX + nn] + acc[mi][ni][j];
                }
                int nl = wv * 32 + ni * 16 + ln;
                int ml = mi * 16 + kg * 4;
                *(f32x4*)&xT[nl * 68 + ml] = tv;
            }
        __syncthreads();
        int nl = t >> 1, seg = t & 1;
#pragma unroll
        for (int q = 0; q < 8; ++q) {
            f32x4 v = *(const f32x4*)&xT[nl * 68 + seg * 32 + q * 4];
            *(f32x4*)&out[(long)(n0 + nl) * NATOMS + m0 + seg * 32 + q * 4] = v;
        }
    }
}

// ---------------------------------------------------------------------------
extern "C" void kernel_launch(void* const* d_in, const int* in_sizes, int n_in,
                              void* d_out, int out_size, void* d_ws, size_t ws_size,
                              hipStream_t stream) {
    const float* Y = (const float*)d_in[0];   // [4096][256]
    const float* A = (const float*)d_in[1];   // [256][512]

    // ws layout (float units), lifetime-checked overlays; total 6946816 floats
    // = 26.5 MiB (r3-r7 proven footprint).
    float* ws = (float*)d_ws;
    double* Gd  = (double*)(ws + 0);        // [0,131072)       dead after step 5
    float*  Gf  = ws + 131072;              // [131072,196608)  dead after sweep
    float*  X0f = ws + 196608;              // [196608,262144)  dead after step 4
    double* X1d = (double*)(ws + 262144);   // [262144,393216)  dead after step 6
    double* Pd  = (double*)(ws + 393216);   // [393216,524288)  dead after step 6
    double* X2d = (double*)(ws + 131072);   // overlays Gf+X0f (both dead)
    double* Hd  = (double*)(ws + 393216);   // [393216,655360) overlays Pd (dead)
    float*  xbuf = ws + 655360;             // [655360,2752512) fp32 x state
    unsigned short* Whg = (unsigned short*)(ws + 0);        // overlays Gd (dead)
    unsigned short* Wlg = (unsigned short*)(ws + 131072);   // overlays X2d (dead after h)
    unsigned short* DAh = (unsigned short*)(ws + 2752512);
    unsigned short* DAl = (unsigned short*)(ws + 3801088);
    unsigned short* DBh = (unsigned short*)(ws + 4849664);
    unsigned short* DBl = (unsigned short*)(ws + 5898240);  // end 6946816
    float* vbuf = (float*)d_out;   // v_k fp32, iters 1..29 (d_out as scratch)
    float* outp = (float*)d_out;   // final output, written by LAST iter only

    g_kernel_d<<<256, 256, 0, stream>>>(A, Gd, Gf);                 // 1
    sweep_blk512<<<1, 512, 0, stream>>>(Gf, X0f);                   // 2
    mm_gd<float><<<256, 256, 0, stream>>>(Gd, X0f, Pd);             // 3
    upd_newton<float><<<256, 256, 0, stream>>>(X0f, Pd, X1d);       // 4
    mm_gd<double><<<256, 256, 0, stream>>>(Gd, X1d, Pd);            // 5
    upd_newton<double><<<256, 256, 0, stream>>>(X1d, Pd, X2d);      // 6
    h_kernel_d<<<256, 256, 0, stream>>>(X2d, A, Hd);                // 7
    w_kernel_d<<<512, 256, 0, stream>>>(A, Hd, Whg, Wlg);           // 8
    aty_kernel<<<dim3(64, 8), 256, 0, stream>>>(A, Y, DAh, DAl);    // 9

    dim3 ig(NVOX / 128, NATOMS / 64);  // (32, 8) = 256 blocks
    unsigned short *ch = DAh, *cl = DAl, *nh = DBh, *nl = DBl;
    // iter 1: Delta_0 = AtY; x1 = W*AtY; v1 = x1; Delta_1 = g(v1)
    admm_delta<1, 0><<<ig, 256, 0, stream>>>(Whg, Wlg, ch, cl, xbuf, vbuf, nh, nl, nullptr);
    { unsigned short* s; s = ch; ch = nh; nh = s; s = cl; cl = nl; nl = s; }
    for (int it = 2; it <= NITER - 1; ++it) {
        admm_delta<0, 0><<<ig, 256, 0, stream>>>(Whg, Wlg, ch, cl, xbuf, vbuf, nh, nl, nullptr);
        unsigned short* s; s = ch; ch = nh; nh = s; s = cl; cl = nl; nl = s;
    }
    // iter 30: x30 = x29 + W*Delta_29, written transposed to d_out
    admm_delta<0, 1><<<ig, 256, 0, stream>>>(Whg, Wlg, ch, cl, xbuf, vbuf, nullptr, nullptr, outp);
}